// Round 3
// baseline (525.261 us; speedup 1.0000x reference)
//
#include <hip/hip_runtime.h>
#include <hip/hip_bf16.h>
#include <stdint.h>

// MoE FFN, top-1 routing. x:[4,2048,1024] f32, 8 experts, 1024->4096->1024.
// R3: 8-phase 256x256 counted-vmcnt MFMA GEMMs (T2 swizzle + T3/T4 + T5).

#define D_MODEL 1024
#define D_FF    4096
#define NEXP    8
#define NTOK    8192
#define MAXT256 40

typedef __attribute__((ext_vector_type(8))) short bf16x8;
typedef __attribute__((ext_vector_type(8))) unsigned short u16x8;
typedef __attribute__((ext_vector_type(4))) float f32x4;

// ---- workspace layout (bytes) ----
#define OFF_META 0u
#define OFF_TOPI 4096u
#define OFF_PERM (4096u + 32768u)
#define OFF_XG   131072u                     // 8448*1024*2 = 17301504
#define OFF_H    17432576u                   // 8448*4096*2 = 69206016
#define OFF_W1T  86638592u                   // 8*4096*1024*2
#define OFF_W2T  153747456u                  // 8*1024*4096*2  (end ~210.6 MB)

__device__ __forceinline__ unsigned short f2bf(float f) {
  unsigned int u = __builtin_bit_cast(unsigned int, f);
  unsigned int r = (u + 0x7FFFu + ((u >> 16) & 1u)) >> 16;
  return (unsigned short)r;
}

typedef const __attribute__((address_space(1))) unsigned int* gas_u32;
typedef __attribute__((address_space(3))) unsigned int* las_u32;

__device__ __forceinline__ void gload16(const void* g, void* l) {
  __builtin_amdgcn_global_load_lds((gas_u32)g, (las_u32)l, 16, 0, 0);
}

__device__ __forceinline__ int xcd_swz(int orig, int nwg) {
  int q = nwg >> 3, r = nwg & 7;
  int xcd = orig & 7, lid = orig >> 3;
  return (xcd < r ? xcd * (q + 1) : r * (q + 1) + (xcd - r) * q) + lid;
}

// ---------------- gating: one wave per token, fp64 accumulate ----------------
__global__ __launch_bounds__(256) void gate_kernel(const float* __restrict__ x,
    const float* __restrict__ gw, const float* __restrict__ gb,
    const float* __restrict__ eb, int* __restrict__ meta, int* __restrict__ topi) {
  int wid = threadIdx.x >> 6, lane = threadIdx.x & 63;
  int t = blockIdx.x * 4 + wid;
  const float* xr = x + (size_t)t * D_MODEL;
  double p[NEXP];
#pragma unroll
  for (int e = 0; e < NEXP; ++e) p[e] = 0.0;
#pragma unroll
  for (int j = 0; j < D_MODEL / 64; ++j) {
    int c = lane + j * 64;
    double xv = (double)xr[c];
#pragma unroll
    for (int e = 0; e < NEXP; ++e) p[e] += xv * (double)gw[e * D_MODEL + c];
  }
#pragma unroll
  for (int e = 0; e < NEXP; ++e) {
    for (int off = 32; off; off >>= 1) p[e] += __shfl_xor(p[e], off, 64);
  }
  if (lane == 0) {
    double best = -1e300; int bi = 0;
#pragma unroll
    for (int e = 0; e < NEXP; ++e) {
      double v = p[e] + (double)gb[e] + (double)eb[e];
      if (v > best) { best = v; bi = e; }
    }
    topi[t] = bi;
    atomicAdd(meta + bi, 1);
  }
}

__global__ void init_kernel(int* meta) {
  if (threadIdx.x < 8) meta[threadIdx.x] = 0;
}

__global__ void scan_kernel(int* meta) {
  int* counts = meta; int* offs = meta + 8; int* fill = meta + 17;
  int* tileE = meta + 32; int* tileM = meta + 112;
  offs[0] = 0;
  int nt = 0;
  for (int e = 0; e < NEXP; ++e) {
    offs[e + 1] = offs[e] + counts[e];
    fill[e] = 0;
    int ntile = (counts[e] + 255) >> 8;       // 256-row tiles
    for (int j = 0; j < ntile; ++j) { tileE[nt] = e; tileM[nt] = j; ++nt; }
  }
  meta[25] = nt;
}

// -------- scatter tokens into per-expert contiguous rows, f32 -> bf16 --------
__global__ __launch_bounds__(256) void scatter_kernel(const float* __restrict__ x,
    const int* __restrict__ topi, int* __restrict__ meta, int* __restrict__ perm,
    unsigned short* __restrict__ xg) {
  __shared__ int spos;
  int t = blockIdx.x;
  if (threadIdx.x == 0) {
    int e = topi[t];
    int p = meta[8 + e] + atomicAdd(meta + 17 + e, 1);
    perm[p] = t;
    spos = p;
  }
  __syncthreads();
  int pos = spos;
  const float* xr = x + (size_t)t * D_MODEL;
  unsigned short* orow = xg + (size_t)pos * D_MODEL;
#pragma unroll
  for (int j = 0; j < 4; ++j) {
    int c = threadIdx.x + j * 256;
    orow[c] = f2bf(xr[c]);
  }
}

// ---- weight convert+transpose: [E][R][C] f32 -> [E][C][R] bf16 ----
__global__ __launch_bounds__(256) void transconv2(const float* __restrict__ in,
    unsigned short* __restrict__ out, int R, int C) {
  __shared__ float tile[64][65];
  int e = blockIdx.z;
  const float* src = in + (size_t)e * R * C;
  unsigned short* dst = out + (size_t)e * R * C;
  int c0 = blockIdx.x * 64, r0 = blockIdx.y * 64;
  int tid = threadIdx.x;
  int rr = tid >> 4, cc4 = (tid & 15) * 4;
#pragma unroll
  for (int i = 0; i < 4; ++i) {
    f32x4 v = *(const f32x4*)(src + (size_t)(r0 + rr + i * 16) * C + c0 + cc4);
#pragma unroll
    for (int j = 0; j < 4; ++j) tile[rr + i * 16][cc4 + j] = v[j];
  }
  __syncthreads();
  int cc = tid >> 3, rr8 = (tid & 7) * 8;
#pragma unroll
  for (int i = 0; i < 2; ++i) {
    int c = cc + i * 32;
    u16x8 u;
#pragma unroll
    for (int j = 0; j < 8; ++j) u[j] = f2bf(tile[rr8 + j][c]);
    *(u16x8*)(dst + (size_t)(c0 + c) * R + r0 + rr8) = u;
  }
}

// ---------------- 8-phase 256x256 grouped GEMM (bf16 MFMA) ------------------
// A [rows][KDIM] bf16, Bt [E][NDIM][KDIM] bf16. 8 waves 2Mx4N, BK=64.
// LDS 128KB: 2 dbuf x { A:[mh0|mh1] 16KB each, B:[nh0|nh1] 16KB each }.
// Phases (mh,nh): (0,0),(0,1),(1,1),(1,0).  Stage slots per tile T:
//   p1: A1(T+1)  p2: B0(T+1)  -> other buf (idle since T-1)
//   p3: A0(T+2)  p4: B1(T+2)  -> current buf, region freed by phase order
// vmcnt(4) at p4 end leaves {A0(T+2),B1(T+2)} in flight; everything tile T+1
// reads is guaranteed landed. Never drains to 0 (T4).
#define SBAR() { __builtin_amdgcn_sched_barrier(0); __builtin_amdgcn_s_barrier(); __builtin_amdgcn_sched_barrier(0); }
#define WAIT_VM(N) { asm volatile("s_waitcnt vmcnt(" #N ")" ::: "memory"); __builtin_amdgcn_sched_barrier(0); }

template<int KDIM, int NDIM, bool IS_FFN1>
__global__ __launch_bounds__(512, 2) void gemm8(
    const unsigned short* __restrict__ A, const unsigned short* __restrict__ Bt,
    const float* __restrict__ bias, const int* __restrict__ meta,
    const int* __restrict__ perm, unsigned short* __restrict__ H,
    float* __restrict__ Out) {
  constexpr int NT = KDIM / 64;
  constexpr int SK = KDIM * 2;               // K-major row stride (bytes)
  const int NP = NDIM / 256;
  int ntiles = meta[25];
  int nwg = ntiles * NP;
  int orig = blockIdx.x;
  if (orig >= nwg) return;
  int wid = xcd_swz(orig, nwg);
  int t = wid % ntiles, nb = wid / ntiles;

  int e = meta[32 + t];
  int lm = meta[112 + t];
  int off = meta[8 + e];
  int rowsValid = meta[9 + e] - off - lm * 256;
  int m0 = off + lm * 256;

  __shared__ char lds[131072];

  int tid = threadIdx.x;
  int lane = tid & 63, wv = tid >> 6;
  int waveM = wv >> 2, waveN = wv & 3;       // 2M x 4N
  int lr = lane & 15, lg = lane >> 4;

  const char* aBase = (const char*)(A + (size_t)m0 * KDIM);
  const char* bBase = (const char*)(Bt + ((size_t)e * NDIM + nb * 256) * KDIM);

  // staging: thread writes LDS bytes [o0,o0+16) and [o1,o1+16) of a 16KB half.
  // source col pre-swizzled (rule #21); reads apply the same XOR (st_16x32).
  const int o0 = tid * 16, o1 = o0 + 8192;
  const int lw0 = o0 >> 7, lw1 = o1 >> 7;
  const int co0 = (o0 & 127) ^ (((o0 >> 9) & 1) << 5);
  const int co1 = (o1 & 127) ^ (((o1 >> 9) & 1) << 5);
  const int mA0 = (lw0 >> 6) * 128 + (lw0 & 63), mA1 = (lw1 >> 6) * 128 + (lw1 & 63);
  const int nB0 = (lw0 >> 5) * 64 + (lw0 & 31), nB1 = (lw1 >> 5) * 64 + (lw1 & 31);

#define ST_A(D, R, KT) { \
    char* _d = lds + (D) * 65536 + (R) * 16384; \
    gload16(aBase + (size_t)(mA0 + (R) * 64) * SK + (KT) * 128 + co0, _d + o0); \
    gload16(aBase + (size_t)(mA1 + (R) * 64) * SK + (KT) * 128 + co1, _d + o1); }
#define ST_B(D, R, KT) { \
    char* _d = lds + (D) * 65536 + 32768 + (R) * 16384; \
    gload16(bBase + (size_t)(nB0 + (R) * 32) * SK + (KT) * 128 + co0, _d + o0); \
    gload16(bBase + (size_t)(nB1 + (R) * 32) * SK + (KT) * 128 + co1, _d + o1); }

  bf16x8 a[4][2], b[2][2];
#define LD_A(D, MH) { \
    const char* _b = lds + (D) * 65536 + (MH) * 16384; \
    _Pragma("unroll") for (int mfi = 0; mfi < 4; ++mfi) \
    _Pragma("unroll") for (int ks = 0; ks < 2; ++ks) { \
      int _o = (waveM * 64 + mfi * 16 + lr) * 128 + ks * 64 + lg * 16; \
      _o ^= ((_o >> 9) & 1) << 5; \
      a[mfi][ks] = *(const bf16x8*)(_b + _o); } }
#define LD_B(D, NH) { \
    const char* _b = lds + (D) * 65536 + 32768 + (NH) * 16384; \
    _Pragma("unroll") for (int nfi = 0; nfi < 2; ++nfi) \
    _Pragma("unroll") for (int ks = 0; ks < 2; ++ks) { \
      int _o = (waveN * 32 + nfi * 16 + lr) * 128 + ks * 64 + lg * 16; \
      _o ^= ((_o >> 9) & 1) << 5; \
      b[nfi][ks] = *(const bf16x8*)(_b + _o); } }

  f32x4 acc[8][4];
#pragma unroll
  for (int i = 0; i < 8; ++i)
#pragma unroll
    for (int j = 0; j < 4; ++j) acc[i][j] = (f32x4){0.f, 0.f, 0.f, 0.f};

#define MM(MH, NH) { \
    __builtin_amdgcn_s_setprio(1); \
    _Pragma("unroll") for (int mfi = 0; mfi < 4; ++mfi) \
    _Pragma("unroll") for (int nfi = 0; nfi < 2; ++nfi) \
    _Pragma("unroll") for (int ks = 0; ks < 2; ++ks) \
      acc[(MH) * 4 + mfi][(NH) * 2 + nfi] = __builtin_amdgcn_mfma_f32_16x16x32_bf16( \
          a[mfi][ks], b[nfi][ks], acc[(MH) * 4 + mfi][(NH) * 2 + nfi], 0, 0, 0); \
    __builtin_amdgcn_s_setprio(0); }

  // prologue: tile0 fully + tile1's {A0,B1}; wait so tile0 landed (4 left).
  ST_A(0, 0, 0); ST_B(0, 1, 0); ST_A(0, 1, 0); ST_B(0, 0, 0);
  {
    int k1 = NT > 1 ? 1 : 0;
    ST_A(1, 0, k1); ST_B(1, 1, k1);
  }
  WAIT_VM(4); SBAR();

  for (int T = 0; T < NT; ++T) {
    int d = T & 1, dn = d ^ 1;
    int tp1 = T + 1 < NT ? T + 1 : T;      // clamped: keeps vmcnt counts exact
    int tp2 = T + 2 < NT ? T + 2 : T;
    // p1 (mh0, nh0)
    LD_A(d, 0); LD_B(d, 0);
    ST_A(dn, 1, tp1);
    SBAR();
    MM(0, 0);
    SBAR();
    // p2 (mh0, nh1)
    LD_B(d, 1);
    ST_B(dn, 0, tp1);
    SBAR();
    MM(0, 1);
    SBAR();
    // p3 (mh1, nh1)
    LD_A(d, 1);
    ST_A(d, 0, tp2);                       // A0 region freed after p2
    SBAR();
    MM(1, 1);
    SBAR();
    // p4 (mh1, nh0)
    LD_B(d, 0);
    ST_B(d, 1, tp2);                       // B1 region freed after p3
    SBAR();
    MM(1, 0);
    WAIT_VM(4);
    SBAR();
  }
  asm volatile("s_waitcnt vmcnt(0)" ::: "memory");

  // epilogue: C/D map col=lane&15, row=(lane>>4)*4+reg
  int cb = nb * 256 + waveN * 64;
#pragma unroll
  for (int mf = 0; mf < 8; ++mf) {
#pragma unroll
    for (int rg = 0; rg < 4; ++rg) {
      int rowt = waveM * 128 + mf * 16 + lg * 4 + rg;
      if (rowt >= rowsValid) continue;
      if (IS_FFN1) {
        size_t ro = (size_t)(m0 + rowt) * NDIM;
#pragma unroll
        for (int nf = 0; nf < 4; ++nf) {
          int col = cb + nf * 16 + lr;
          float v = acc[mf][nf][rg] + bias[e * NDIM + col];
          H[ro + col] = f2bf(fmaxf(v, 0.f));
        }
      } else {
        int tok = perm[m0 + rowt];
        size_t ro = (size_t)tok * NDIM;
#pragma unroll
        for (int nf = 0; nf < 4; ++nf) {
          int col = cb + nf * 16 + lr;
          Out[ro + col] = acc[mf][nf][rg] + bias[e * NDIM + col];
        }
      }
    }
  }
#undef ST_A
#undef ST_B
#undef LD_A
#undef LD_B
#undef MM
}

extern "C" void kernel_launch(void* const* d_in, const int* in_sizes, int n_in,
                              void* d_out, int out_size, void* d_ws, size_t ws_size,
                              hipStream_t stream) {
  const float* x  = (const float*)d_in[0];
  const float* gw = (const float*)d_in[1];
  const float* gb = (const float*)d_in[2];
  const float* eb = (const float*)d_in[3];
  const float* w1 = (const float*)d_in[4];
  const float* b1 = (const float*)d_in[5];
  const float* w2 = (const float*)d_in[6];
  const float* b2 = (const float*)d_in[7];
  float* out = (float*)d_out;

  char* ws = (char*)d_ws;
  int* meta = (int*)(ws + OFF_META);
  int* topi = (int*)(ws + OFF_TOPI);
  int* perm = (int*)(ws + OFF_PERM);
  unsigned short* xg  = (unsigned short*)(ws + OFF_XG);
  unsigned short* h   = (unsigned short*)(ws + OFF_H);
  unsigned short* w1t = (unsigned short*)(ws + OFF_W1T);
  unsigned short* w2t = (unsigned short*)(ws + OFF_W2T);

  hipLaunchKernelGGL(init_kernel, dim3(1), dim3(64), 0, stream, meta);
  hipLaunchKernelGGL(gate_kernel, dim3(NTOK / 4), dim3(256), 0, stream, x, gw, gb, eb, meta, topi);
  hipLaunchKernelGGL(scan_kernel, dim3(1), dim3(1), 0, stream, meta);
  hipLaunchKernelGGL(scatter_kernel, dim3(NTOK), dim3(256), 0, stream, x, topi, meta, perm, xg);
  hipLaunchKernelGGL(transconv2, dim3(D_FF / 64, D_MODEL / 64, NEXP), dim3(256), 0, stream,
                     w1, w1t, D_MODEL, D_FF);
  hipLaunchKernelGGL(transconv2, dim3(D_MODEL / 64, D_FF / 64, NEXP), dim3(256), 0, stream,
                     w2, w2t, D_FF, D_MODEL);
  hipLaunchKernelGGL((gemm8<D_MODEL, D_FF, true>), dim3(MAXT256 * (D_FF / 256)), dim3(512), 0, stream,
                     xg, w1t, b1, meta, perm, h, nullptr);
  hipLaunchKernelGGL((gemm8<D_FF, D_MODEL, false>), dim3(MAXT256 * (D_MODEL / 256)), dim3(512), 0, stream,
                     h, w2t, b2, meta, perm, nullptr, out);
}

// Round 4
// 502.971 us; speedup vs baseline: 1.0443x; 1.0443x over previous
//
#include <hip/hip_runtime.h>
#include <hip/hip_bf16.h>
#include <stdint.h>

// MoE FFN, top-1 routing. x:[4,2048,1024] f32, 8 experts, 1024->4096->1024.
// R4: fix LDS swizzle to (row&7)<<4 XOR (16B-slot spread for 128B-row tiles).

#define D_MODEL 1024
#define D_FF    4096
#define NEXP    8
#define NTOK    8192
#define MAXT256 40

typedef __attribute__((ext_vector_type(8))) short bf16x8;
typedef __attribute__((ext_vector_type(8))) unsigned short u16x8;
typedef __attribute__((ext_vector_type(4))) float f32x4;

// ---- workspace layout (bytes) ----
#define OFF_META 0u
#define OFF_TOPI 4096u
#define OFF_PERM (4096u + 32768u)
#define OFF_XG   131072u                     // 8448*1024*2
#define OFF_H    17432576u                   // 8448*4096*2
#define OFF_W1T  86638592u                   // 8*4096*1024*2
#define OFF_W2T  153747456u                  // 8*1024*4096*2

__device__ __forceinline__ unsigned short f2bf(float f) {
  unsigned int u = __builtin_bit_cast(unsigned int, f);
  unsigned int r = (u + 0x7FFFu + ((u >> 16) & 1u)) >> 16;
  return (unsigned short)r;
}

typedef const __attribute__((address_space(1))) unsigned int* gas_u32;
typedef __attribute__((address_space(3))) unsigned int* las_u32;

__device__ __forceinline__ void gload16(const void* g, void* l) {
  __builtin_amdgcn_global_load_lds((gas_u32)g, (las_u32)l, 16, 0, 0);
}

__device__ __forceinline__ int xcd_swz(int orig, int nwg) {
  int q = nwg >> 3, r = nwg & 7;
  int xcd = orig & 7, lid = orig >> 3;
  return (xcd < r ? xcd * (q + 1) : r * (q + 1) + (xcd - r) * q) + lid;
}

// ---------------- gating: one wave per token, fp64 accumulate ----------------
__global__ __launch_bounds__(256) void gate_kernel(const float* __restrict__ x,
    const float* __restrict__ gw, const float* __restrict__ gb,
    const float* __restrict__ eb, int* __restrict__ meta, int* __restrict__ topi) {
  int wid = threadIdx.x >> 6, lane = threadIdx.x & 63;
  int t = blockIdx.x * 4 + wid;
  const float* xr = x + (size_t)t * D_MODEL;
  double p[NEXP];
#pragma unroll
  for (int e = 0; e < NEXP; ++e) p[e] = 0.0;
#pragma unroll
  for (int j = 0; j < D_MODEL / 64; ++j) {
    int c = lane + j * 64;
    double xv = (double)xr[c];
#pragma unroll
    for (int e = 0; e < NEXP; ++e) p[e] += xv * (double)gw[e * D_MODEL + c];
  }
#pragma unroll
  for (int e = 0; e < NEXP; ++e) {
    for (int off = 32; off; off >>= 1) p[e] += __shfl_xor(p[e], off, 64);
  }
  if (lane == 0) {
    double best = -1e300; int bi = 0;
#pragma unroll
    for (int e = 0; e < NEXP; ++e) {
      double v = p[e] + (double)gb[e] + (double)eb[e];
      if (v > best) { best = v; bi = e; }
    }
    topi[t] = bi;
    atomicAdd(meta + bi, 1);
  }
}

__global__ void init_kernel(int* meta) {
  if (threadIdx.x < 8) meta[threadIdx.x] = 0;
}

__global__ void scan_kernel(int* meta) {
  int* counts = meta; int* offs = meta + 8; int* fill = meta + 17;
  int* tileE = meta + 32; int* tileM = meta + 112;
  offs[0] = 0;
  int nt = 0;
  for (int e = 0; e < NEXP; ++e) {
    offs[e + 1] = offs[e] + counts[e];
    fill[e] = 0;
    int ntile = (counts[e] + 255) >> 8;
    for (int j = 0; j < ntile; ++j) { tileE[nt] = e; tileM[nt] = j; ++nt; }
  }
  meta[25] = nt;
}

// -------- scatter tokens into per-expert contiguous rows, f32 -> bf16 --------
__global__ __launch_bounds__(256) void scatter_kernel(const float* __restrict__ x,
    const int* __restrict__ topi, int* __restrict__ meta, int* __restrict__ perm,
    unsigned short* __restrict__ xg) {
  __shared__ int spos;
  int t = blockIdx.x;
  if (threadIdx.x == 0) {
    int e = topi[t];
    int p = meta[8 + e] + atomicAdd(meta + 17 + e, 1);
    perm[p] = t;
    spos = p;
  }
  __syncthreads();
  int pos = spos;
  const float* xr = x + (size_t)t * D_MODEL;
  unsigned short* orow = xg + (size_t)pos * D_MODEL;
#pragma unroll
  for (int j = 0; j < 4; ++j) {
    int c = threadIdx.x + j * 256;
    orow[c] = f2bf(xr[c]);
  }
}

// ---- weight convert+transpose: [E][R][C] f32 -> [E][C][R] bf16 ----
__global__ __launch_bounds__(256) void transconv2(const float* __restrict__ in,
    unsigned short* __restrict__ out, int R, int C) {
  __shared__ float tile[64][65];
  int e = blockIdx.z;
  const float* src = in + (size_t)e * R * C;
  unsigned short* dst = out + (size_t)e * R * C;
  int c0 = blockIdx.x * 64, r0 = blockIdx.y * 64;
  int tid = threadIdx.x;
  int rr = tid >> 4, cc4 = (tid & 15) * 4;
#pragma unroll
  for (int i = 0; i < 4; ++i) {
    f32x4 v = *(const f32x4*)(src + (size_t)(r0 + rr + i * 16) * C + c0 + cc4);
#pragma unroll
    for (int j = 0; j < 4; ++j) tile[rr + i * 16][cc4 + j] = v[j];
  }
  __syncthreads();
  int cc = tid >> 3, rr8 = (tid & 7) * 8;
#pragma unroll
  for (int i = 0; i < 2; ++i) {
    int c = cc + i * 32;
    u16x8 u;
#pragma unroll
    for (int j = 0; j < 8; ++j) u[j] = f2bf(tile[rr8 + j][c]);
    *(u16x8*)(dst + (size_t)(c0 + c) * R + r0 + rr8) = u;
  }
}

// ---------------- 8-phase 256x256 grouped GEMM (bf16 MFMA) ------------------
// A [rows][KDIM] bf16, Bt [E][NDIM][KDIM] bf16. 8 waves 2Mx4N, BK=64.
// LDS 128KB: 2 dbuf x { A:[mh0|mh1] 16KB each, B:[nh0|nh1] 16KB each }.
// Swizzle: addr ^= ((row&7)<<4) within each 128B-row region (involution;
// applied to stage-source AND ds_read per rule #21).
#define SBAR() { __builtin_amdgcn_sched_barrier(0); __builtin_amdgcn_s_barrier(); __builtin_amdgcn_sched_barrier(0); }
#define WAIT_VM(N) { asm volatile("s_waitcnt vmcnt(" #N ")" ::: "memory"); __builtin_amdgcn_sched_barrier(0); }

template<int KDIM, int NDIM, bool IS_FFN1>
__global__ __launch_bounds__(512, 2) void gemm8(
    const unsigned short* __restrict__ A, const unsigned short* __restrict__ Bt,
    const float* __restrict__ bias, const int* __restrict__ meta,
    const int* __restrict__ perm, unsigned short* __restrict__ H,
    float* __restrict__ Out) {
  constexpr int NT = KDIM / 64;
  constexpr int SK = KDIM * 2;
  const int NP = NDIM / 256;
  int ntiles = meta[25];
  int nwg = ntiles * NP;
  int orig = blockIdx.x;
  if (orig >= nwg) return;
  int wid = xcd_swz(orig, nwg);
  int t = wid % ntiles, nb = wid / ntiles;

  int e = meta[32 + t];
  int lm = meta[112 + t];
  int off = meta[8 + e];
  int rowsValid = meta[9 + e] - off - lm * 256;
  int m0 = off + lm * 256;

  __shared__ char lds[131072];

  int tid = threadIdx.x;
  int lane = tid & 63, wv = tid >> 6;
  int waveM = wv >> 2, waveN = wv & 3;       // 2M x 4N
  int lr = lane & 15, lg = lane >> 4;

  const char* aBase = (const char*)(A + (size_t)m0 * KDIM);
  const char* bBase = (const char*)(Bt + ((size_t)e * NDIM + nb * 256) * KDIM);

  // staging: thread writes LDS bytes [o0,o0+16) and [o1,o1+16) of a 16KB half.
  // source col carries the inverse (== same) swizzle: co = (o&127) ^ ((row&7)<<4)
  const int o0 = tid * 16, o1 = o0 + 8192;
  const int lw0 = o0 >> 7, lw1 = o1 >> 7;
  const int co0 = (o0 & 127) ^ ((lw0 & 7) << 4);
  const int co1 = (o1 & 127) ^ ((lw1 & 7) << 4);
  const int mA0 = (lw0 >> 6) * 128 + (lw0 & 63), mA1 = (lw1 >> 6) * 128 + (lw1 & 63);
  const int nB0 = (lw0 >> 5) * 64 + (lw0 & 31), nB1 = (lw1 >> 5) * 64 + (lw1 & 31);

#define ST_A(D, R, KT) { \
    char* _d = lds + (D) * 65536 + (R) * 16384; \
    gload16(aBase + (size_t)(mA0 + (R) * 64) * SK + (KT) * 128 + co0, _d + o0); \
    gload16(aBase + (size_t)(mA1 + (R) * 64) * SK + (KT) * 128 + co1, _d + o1); }
#define ST_B(D, R, KT) { \
    char* _d = lds + (D) * 65536 + 32768 + (R) * 16384; \
    gload16(bBase + (size_t)(nB0 + (R) * 32) * SK + (KT) * 128 + co0, _d + o0); \
    gload16(bBase + (size_t)(nB1 + (R) * 32) * SK + (KT) * 128 + co1, _d + o1); }

  bf16x8 a[4][2], b[2][2];
#define LD_A(D, MH) { \
    const char* _b = lds + (D) * 65536 + (MH) * 16384; \
    _Pragma("unroll") for (int mfi = 0; mfi < 4; ++mfi) \
    _Pragma("unroll") for (int ks = 0; ks < 2; ++ks) { \
      int _o = (waveM * 64 + mfi * 16 + lr) * 128 + ks * 64 + lg * 16; \
      _o ^= ((_o >> 7) & 7) << 4; \
      a[mfi][ks] = *(const bf16x8*)(_b + _o); } }
#define LD_B(D, NH) { \
    const char* _b = lds + (D) * 65536 + 32768 + (NH) * 16384; \
    _Pragma("unroll") for (int nfi = 0; nfi < 2; ++nfi) \
    _Pragma("unroll") for (int ks = 0; ks < 2; ++ks) { \
      int _o = (waveN * 32 + nfi * 16 + lr) * 128 + ks * 64 + lg * 16; \
      _o ^= ((_o >> 7) & 7) << 4; \
      b[nfi][ks] = *(const bf16x8*)(_b + _o); } }

  f32x4 acc[8][4];
#pragma unroll
  for (int i = 0; i < 8; ++i)
#pragma unroll
    for (int j = 0; j < 4; ++j) acc[i][j] = (f32x4){0.f, 0.f, 0.f, 0.f};

#define MM(MH, NH) { \
    __builtin_amdgcn_s_setprio(1); \
    _Pragma("unroll") for (int mfi = 0; mfi < 4; ++mfi) \
    _Pragma("unroll") for (int nfi = 0; nfi < 2; ++nfi) \
    _Pragma("unroll") for (int ks = 0; ks < 2; ++ks) \
      acc[(MH) * 4 + mfi][(NH) * 2 + nfi] = __builtin_amdgcn_mfma_f32_16x16x32_bf16( \
          a[mfi][ks], b[nfi][ks], acc[(MH) * 4 + mfi][(NH) * 2 + nfi], 0, 0, 0); \
    __builtin_amdgcn_s_setprio(0); }

  // prologue: tile0 fully + tile1's {A0,B1}; vmcnt(4) -> tile0 landed.
  ST_A(0, 0, 0); ST_B(0, 1, 0); ST_A(0, 1, 0); ST_B(0, 0, 0);
  {
    int k1 = NT > 1 ? 1 : 0;
    ST_A(1, 0, k1); ST_B(1, 1, k1);
  }
  WAIT_VM(4); SBAR();

  for (int T = 0; T < NT; ++T) {
    int d = T & 1, dn = d ^ 1;
    int tp1 = T + 1 < NT ? T + 1 : T;
    int tp2 = T + 2 < NT ? T + 2 : T;
    // p1 (mh0, nh0)
    LD_A(d, 0); LD_B(d, 0);
    ST_A(dn, 1, tp1);
    SBAR();
    MM(0, 0);
    SBAR();
    // p2 (mh0, nh1)
    LD_B(d, 1);
    ST_B(dn, 0, tp1);
    SBAR();
    MM(0, 1);
    SBAR();
    // p3 (mh1, nh1)
    LD_A(d, 1);
    ST_A(d, 0, tp2);
    SBAR();
    MM(1, 1);
    SBAR();
    // p4 (mh1, nh0)
    LD_B(d, 0);
    ST_B(d, 1, tp2);
    SBAR();
    MM(1, 0);
    WAIT_VM(4);
    SBAR();
  }
  asm volatile("s_waitcnt vmcnt(0)" ::: "memory");

  // epilogue: C/D map col=lane&15, row=(lane>>4)*4+reg
  int cb = nb * 256 + waveN * 64;
#pragma unroll
  for (int mf = 0; mf < 8; ++mf) {
#pragma unroll
    for (int rg = 0; rg < 4; ++rg) {
      int rowt = waveM * 128 + mf * 16 + lg * 4 + rg;
      if (rowt >= rowsValid) continue;
      if (IS_FFN1) {
        size_t ro = (size_t)(m0 + rowt) * NDIM;
#pragma unroll
        for (int nf = 0; nf < 4; ++nf) {
          int col = cb + nf * 16 + lr;
          float v = acc[mf][nf][rg] + bias[e * NDIM + col];
          H[ro + col] = f2bf(fmaxf(v, 0.f));
        }
      } else {
        int tok = perm[m0 + rowt];
        size_t ro = (size_t)tok * NDIM;
#pragma unroll
        for (int nf = 0; nf < 4; ++nf) {
          int col = cb + nf * 16 + lr;
          Out[ro + col] = acc[mf][nf][rg] + bias[e * NDIM + col];
        }
      }
    }
  }
#undef ST_A
#undef ST_B
#undef LD_A
#undef LD_B
#undef MM
}

extern "C" void kernel_launch(void* const* d_in, const int* in_sizes, int n_in,
                              void* d_out, int out_size, void* d_ws, size_t ws_size,
                              hipStream_t stream) {
  const float* x  = (const float*)d_in[0];
  const float* gw = (const float*)d_in[1];
  const float* gb = (const float*)d_in[2];
  const float* eb = (const float*)d_in[3];
  const float* w1 = (const float*)d_in[4];
  const float* b1 = (const float*)d_in[5];
  const float* w2 = (const float*)d_in[6];
  const float* b2 = (const float*)d_in[7];
  float* out = (float*)d_out;

  char* ws = (char*)d_ws;
  int* meta = (int*)(ws + OFF_META);
  int* topi = (int*)(ws + OFF_TOPI);
  int* perm = (int*)(ws + OFF_PERM);
  unsigned short* xg  = (unsigned short*)(ws + OFF_XG);
  unsigned short* h   = (unsigned short*)(ws + OFF_H);
  unsigned short* w1t = (unsigned short*)(ws + OFF_W1T);
  unsigned short* w2t = (unsigned short*)(ws + OFF_W2T);

  hipLaunchKernelGGL(init_kernel, dim3(1), dim3(64), 0, stream, meta);
  hipLaunchKernelGGL(gate_kernel, dim3(NTOK / 4), dim3(256), 0, stream, x, gw, gb, eb, meta, topi);
  hipLaunchKernelGGL(scan_kernel, dim3(1), dim3(1), 0, stream, meta);
  hipLaunchKernelGGL(scatter_kernel, dim3(NTOK), dim3(256), 0, stream, x, topi, meta, perm, xg);
  hipLaunchKernelGGL(transconv2, dim3(D_FF / 64, D_MODEL / 64, NEXP), dim3(256), 0, stream,
                     w1, w1t, D_MODEL, D_FF);
  hipLaunchKernelGGL(transconv2, dim3(D_MODEL / 64, D_FF / 64, NEXP), dim3(256), 0, stream,
                     w2, w2t, D_FF, D_MODEL);
  hipLaunchKernelGGL((gemm8<D_MODEL, D_FF, true>), dim3(MAXT256 * (D_FF / 256)), dim3(512), 0, stream,
                     xg, w1t, b1, meta, perm, h, nullptr);
  hipLaunchKernelGGL((gemm8<D_FF, D_MODEL, false>), dim3(MAXT256 * (D_MODEL / 256)), dim3(512), 0, stream,
                     h, w2t, b2, meta, perm, nullptr, out);
}

// Round 5
// 360.442 us; speedup vs baseline: 1.4573x; 1.3954x over previous
//
#include <hip/hip_runtime.h>
#include <hip/hip_bf16.h>
#include <stdint.h>

// MoE FFN, top-1 routing. x:[4,2048,1024] f32, 8 experts, 1024->4096->1024.
// R5: 128x128 4-wave 2-phase GEMM tiles (2 blk/CU), atomic-free routing.

#define D_MODEL 1024
#define D_FF    4096
#define NEXP    8
#define NTOK    8192
#define MAXT128 72

typedef __attribute__((ext_vector_type(8))) short bf16x8;
typedef __attribute__((ext_vector_type(8))) unsigned short u16x8;
typedef __attribute__((ext_vector_type(4))) unsigned short u16x4;
typedef __attribute__((ext_vector_type(4))) float f32x4;

// ---- workspace layout (bytes) ----
#define OFF_META 0u
#define OFF_TOPI 4096u
#define OFF_PERM 36864u
#define OFF_POS  69632u
#define OFF_XG   131072u                     // 8448*1024*2
#define OFF_H    17432576u                   // 8448*4096*2
#define OFF_W1T  86638592u                   // 8*4096*1024*2
#define OFF_W2T  153747456u                  // 8*1024*4096*2

__device__ __forceinline__ unsigned short f2bf(float f) {
  unsigned int u = __builtin_bit_cast(unsigned int, f);
  unsigned int r = (u + 0x7FFFu + ((u >> 16) & 1u)) >> 16;
  return (unsigned short)r;
}

typedef const __attribute__((address_space(1))) unsigned int* gas_u32;
typedef __attribute__((address_space(3))) unsigned int* las_u32;

__device__ __forceinline__ void gload16(const void* g, void* l) {
  __builtin_amdgcn_global_load_lds((gas_u32)g, (las_u32)l, 16, 0, 0);
}

// ---------------- gating: one wave per token, fp64 accumulate ----------------
__global__ __launch_bounds__(256) void gate_kernel(const float* __restrict__ x,
    const float* __restrict__ gw, const float* __restrict__ gb,
    const float* __restrict__ eb, int* __restrict__ topi) {
  int wid = threadIdx.x >> 6, lane = threadIdx.x & 63;
  int t = blockIdx.x * 4 + wid;
  const float* xr = x + (size_t)t * D_MODEL;
  double p[NEXP];
#pragma unroll
  for (int e = 0; e < NEXP; ++e) p[e] = 0.0;
#pragma unroll
  for (int j = 0; j < D_MODEL / 64; ++j) {
    int c = lane + j * 64;
    double xv = (double)xr[c];
#pragma unroll
    for (int e = 0; e < NEXP; ++e) p[e] += xv * (double)gw[e * D_MODEL + c];
  }
#pragma unroll
  for (int e = 0; e < NEXP; ++e) {
    for (int off = 32; off; off >>= 1) p[e] += __shfl_xor(p[e], off, 64);
  }
  if (lane == 0) {
    double best = -1e300; int bi = 0;
#pragma unroll
    for (int e = 0; e < NEXP; ++e) {
      double v = p[e] + (double)gb[e] + (double)eb[e];
      if (v > best) { best = v; bi = e; }
    }
    topi[t] = bi;
  }
}

// ---- rank kernel: 1 block, 1024 threads. counts/offsets/tilemap/pos/perm ----
__global__ __launch_bounds__(1024) void rank_kernel(const int* __restrict__ topi,
    int* __restrict__ meta, int* __restrict__ pos, int* __restrict__ perm) {
  __shared__ int hist[NEXP][1024];
  __shared__ int offs_s[NEXP + 1];
  int tid = threadIdx.x;
  int te[8], loc[NEXP], run[NEXP];
#pragma unroll
  for (int e = 0; e < NEXP; ++e) loc[e] = 0;
#pragma unroll
  for (int j = 0; j < 8; ++j) {
    te[j] = topi[tid * 8 + j];
#pragma unroll
    for (int e = 0; e < NEXP; ++e) loc[e] += (te[j] == e) ? 1 : 0;
  }
#pragma unroll
  for (int e = 0; e < NEXP; ++e) { run[e] = loc[e]; hist[e][tid] = run[e]; }
  __syncthreads();
  for (int s = 1; s < 1024; s <<= 1) {
    int v[NEXP];
#pragma unroll
    for (int e = 0; e < NEXP; ++e) v[e] = (tid >= s) ? hist[e][tid - s] : 0;
    __syncthreads();
#pragma unroll
    for (int e = 0; e < NEXP; ++e) { run[e] += v[e]; hist[e][tid] = run[e]; }
    __syncthreads();
  }
  if (tid == 1023) {
    int o = 0, nt = 0;
    for (int e = 0; e < NEXP; ++e) {
      offs_s[e] = o;
      meta[e] = run[e];
      meta[8 + e] = o;
      o += run[e];
    }
    offs_s[NEXP] = o; meta[16] = o;
    for (int e = 0; e < NEXP; ++e) {
      int ntile = (run[e] + 127) >> 7;
      for (int j = 0; j < ntile; ++j) { meta[32 + nt] = e; meta[112 + nt] = j; ++nt; }
    }
    meta[25] = nt;
  }
  __syncthreads();
  int base[NEXP];
#pragma unroll
  for (int e = 0; e < NEXP; ++e) base[e] = offs_s[e] + run[e] - loc[e];
#pragma unroll
  for (int j = 0; j < 8; ++j) {
    int tok = tid * 8 + j, pj = 0;
#pragma unroll
    for (int e = 0; e < NEXP; ++e) {
      if (te[j] == e) pj = base[e];
      base[e] += (te[j] == e) ? 1 : 0;
    }
    pos[tok] = pj;
    perm[pj] = tok;
  }
}

// -------- scatter tokens into per-expert contiguous rows, f32 -> bf16 --------
__global__ __launch_bounds__(256) void scatter_kernel(const float* __restrict__ x,
    const int* __restrict__ pos, unsigned short* __restrict__ xg) {
  int t = blockIdx.x;
  int p = pos[t];
  const float* xr = x + (size_t)t * D_MODEL;
  unsigned short* orow = xg + (size_t)p * D_MODEL;
  int c = threadIdx.x * 4;
  f32x4 v = *(const f32x4*)(xr + c);
  u16x4 u;
#pragma unroll
  for (int j = 0; j < 4; ++j) u[j] = f2bf(v[j]);
  *(u16x4*)(orow + c) = u;
}

// ---- weight convert+transpose: [E][R][C] f32 -> [E][C][R] bf16 ----
__global__ __launch_bounds__(256) void transconv2(const float* __restrict__ in,
    unsigned short* __restrict__ out, int R, int C) {
  __shared__ float tile[64][65];
  int e = blockIdx.z;
  const float* src = in + (size_t)e * R * C;
  unsigned short* dst = out + (size_t)e * R * C;
  int c0 = blockIdx.x * 64, r0 = blockIdx.y * 64;
  int tid = threadIdx.x;
  int rr = tid >> 4, cc4 = (tid & 15) * 4;
#pragma unroll
  for (int i = 0; i < 4; ++i) {
    f32x4 v = *(const f32x4*)(src + (size_t)(r0 + rr + i * 16) * C + c0 + cc4);
#pragma unroll
    for (int j = 0; j < 4; ++j) tile[rr + i * 16][cc4 + j] = v[j];
  }
  __syncthreads();
  int cc = tid >> 3, rr8 = (tid & 7) * 8;
#pragma unroll
  for (int i = 0; i < 2; ++i) {
    int c = cc + i * 32;
    u16x8 u;
#pragma unroll
    for (int j = 0; j < 8; ++j) u[j] = f2bf(tile[rr8 + j][c]);
    *(u16x8*)(dst + (size_t)(c0 + c) * R + r0 + rr8) = u;
  }
}

// ------------- 2-phase 128x128 grouped GEMM, 4 waves, 64KB LDS --------------
// A [rows][KDIM] bf16, Bt [E][NDIM][KDIM] bf16. BK=64. 2 blocks/CU.
// LDS buf d (32KB): [A0 8K | A1 8K | B 16K]. Phases: MM(mh0), MM(mh1).
// Stage slots: p1 -> other.{A1,B}(T+1); p2 -> cur.A0(T+2) (freed after p1).
// WAIT_VM(2) at p2 leaves only A0(T+2) in flight -> tile T+1 fully landed.
// Swizzle (both sides): byte ^= ((row&7)<<4)  [row = LDS-local 128B row].
#define SBAR() { __builtin_amdgcn_sched_barrier(0); __builtin_amdgcn_s_barrier(); __builtin_amdgcn_sched_barrier(0); }
#define WAIT_VM(N) { asm volatile("s_waitcnt vmcnt(" #N ")" ::: "memory"); __builtin_amdgcn_sched_barrier(0); }

template<int KDIM, int NDIM, bool IS_FFN1>
__global__ __launch_bounds__(256, 2) void gemm4(
    const unsigned short* __restrict__ A, const unsigned short* __restrict__ Bt,
    const float* __restrict__ bias, const int* __restrict__ meta,
    const int* __restrict__ perm, unsigned short* __restrict__ H,
    float* __restrict__ Out) {
  constexpr int NT = KDIM / 64;
  constexpr int SK = KDIM * 2;
  constexpr int NP = NDIM / 128;
  int ntiles = meta[25];
  int t = blockIdx.x / NP, nb = blockIdx.x % NP;
  if (t >= ntiles) return;

  int e = meta[32 + t];
  int lm = meta[112 + t];
  int off = meta[8 + e];
  int rowsValid = meta[9 + e] - off - lm * 128;
  int m0 = off + lm * 128;

  __shared__ char lds[65536];

  int tid = threadIdx.x;
  int lane = tid & 63, wv = tid >> 6;
  int waveM = wv >> 1, waveN = wv & 1;       // 2M x 2N
  int lr = lane & 15, lg = lane >> 4;

  const char* aBase = (const char*)(A + (size_t)m0 * KDIM);
  const char* bBase = (const char*)(Bt + ((size_t)e * NDIM + nb * 128) * KDIM);

  // A staging: 8KB half = 256 thr x 2 x 16B. B: 16KB = 4 x 16B.
  const int oA0 = tid * 16, oA1 = tid * 16 + 4096;
  const int lwA0 = oA0 >> 7, lwA1 = oA1 >> 7;
  const int coA0 = (oA0 & 127) ^ ((lwA0 & 7) << 4);
  const int coA1 = (oA1 & 127) ^ ((lwA1 & 7) << 4);

#define ST_A(D, R, KT) { \
    char* _d = lds + (D) * 32768 + (R) * 8192; \
    gload16(aBase + (size_t)((R) * 64 + lwA0) * SK + (KT) * 128 + coA0, _d + oA0); \
    gload16(aBase + (size_t)((R) * 64 + lwA1) * SK + (KT) * 128 + coA1, _d + oA1); }
#define ST_B(D, KT) { \
    char* _d = lds + (D) * 32768 + 16384; \
    _Pragma("unroll") for (int _j = 0; _j < 4; ++_j) { \
      int _o = tid * 16 + _j * 4096; \
      int _lw = _o >> 7; \
      int _co = (_o & 127) ^ ((_lw & 7) << 4); \
      gload16(bBase + (size_t)_lw * SK + (KT) * 128 + _co, _d + _o); } }

  bf16x8 a[2][2], b[4][2];
#define LD_A(D, MH) { \
    const char* _b = lds + (D) * 32768 + (MH) * 8192; \
    _Pragma("unroll") for (int mfi = 0; mfi < 2; ++mfi) \
    _Pragma("unroll") for (int ks = 0; ks < 2; ++ks) { \
      int _o = (waveM * 32 + mfi * 16 + lr) * 128 + ks * 64 + lg * 16; \
      _o ^= ((_o >> 7) & 7) << 4; \
      a[mfi][ks] = *(const bf16x8*)(_b + _o); } }
#define LD_B(D) { \
    const char* _b = lds + (D) * 32768 + 16384; \
    _Pragma("unroll") for (int nfi = 0; nfi < 4; ++nfi) \
    _Pragma("unroll") for (int ks = 0; ks < 2; ++ks) { \
      int _o = (waveN * 64 + nfi * 16 + lr) * 128 + ks * 64 + lg * 16; \
      _o ^= ((_o >> 7) & 7) << 4; \
      b[nfi][ks] = *(const bf16x8*)(_b + _o); } }

  f32x4 acc[4][4];
#pragma unroll
  for (int i = 0; i < 4; ++i)
#pragma unroll
    for (int j = 0; j < 4; ++j) acc[i][j] = (f32x4){0.f, 0.f, 0.f, 0.f};

#define MM(MH) { \
    __builtin_amdgcn_s_setprio(1); \
    _Pragma("unroll") for (int mfi = 0; mfi < 2; ++mfi) \
    _Pragma("unroll") for (int nfi = 0; nfi < 4; ++nfi) \
    _Pragma("unroll") for (int ks = 0; ks < 2; ++ks) \
      acc[(MH) * 2 + mfi][nfi] = __builtin_amdgcn_mfma_f32_16x16x32_bf16( \
          a[mfi][ks], b[nfi][ks], acc[(MH) * 2 + mfi][nfi], 0, 0, 0); \
    __builtin_amdgcn_s_setprio(0); }

  // prologue: tile0 {A0,A1,B} + tile1 A0 -> 10 loads; wait(2) = tile0 landed.
  ST_A(0, 0, 0); ST_A(0, 1, 0); ST_B(0, 0);
  {
    int k1 = NT > 1 ? 1 : 0;
    ST_A(1, 0, k1);
  }
  WAIT_VM(2); SBAR();

  for (int T = 0; T < NT; ++T) {
    int d = T & 1, dn = d ^ 1;
    int tp1 = T + 1 < NT ? T + 1 : T;
    int tp2 = T + 2 < NT ? T + 2 : T;
    // p1 (mh0): read A0+B, stage other.{A1,B}(T+1)
    LD_A(d, 0); LD_B(d);
    ST_A(dn, 1, tp1);
    ST_B(dn, tp1);
    SBAR();
    MM(0);
    SBAR();
    // p2 (mh1): read A1, stage cur.A0(T+2)
    LD_A(d, 1);
    ST_A(d, 0, tp2);
    SBAR();
    MM(1);
    WAIT_VM(2);
    SBAR();
  }
  asm volatile("s_waitcnt vmcnt(0)" ::: "memory");

  // epilogue: C/D map col=lane&15, row=(lane>>4)*4+reg
  int cb = nb * 128 + waveN * 64;
#pragma unroll
  for (int mf = 0; mf < 4; ++mf) {
#pragma unroll
    for (int rg = 0; rg < 4; ++rg) {
      int rowt = (mf >> 1) * 64 + waveM * 32 + (mf & 1) * 16 + lg * 4 + rg;
      if (rowt >= rowsValid) continue;
      if (IS_FFN1) {
        size_t ro = (size_t)(m0 + rowt) * NDIM;
#pragma unroll
        for (int nf = 0; nf < 4; ++nf) {
          int col = cb + nf * 16 + lr;
          float v = acc[mf][nf][rg] + bias[e * NDIM + col];
          H[ro + col] = f2bf(fmaxf(v, 0.f));
        }
      } else {
        int tok = perm[m0 + rowt];
        size_t ro = (size_t)tok * NDIM;
#pragma unroll
        for (int nf = 0; nf < 4; ++nf) {
          int col = cb + nf * 16 + lr;
          Out[ro + col] = acc[mf][nf][rg] + bias[e * NDIM + col];
        }
      }
    }
  }
#undef ST_A
#undef ST_B
#undef LD_A
#undef LD_B
#undef MM
}

extern "C" void kernel_launch(void* const* d_in, const int* in_sizes, int n_in,
                              void* d_out, int out_size, void* d_ws, size_t ws_size,
                              hipStream_t stream) {
  const float* x  = (const float*)d_in[0];
  const float* gw = (const float*)d_in[1];
  const float* gb = (const float*)d_in[2];
  const float* eb = (const float*)d_in[3];
  const float* w1 = (const float*)d_in[4];
  const float* b1 = (const float*)d_in[5];
  const float* w2 = (const float*)d_in[6];
  const float* b2 = (const float*)d_in[7];
  float* out = (float*)d_out;

  char* ws = (char*)d_ws;
  int* meta = (int*)(ws + OFF_META);
  int* topi = (int*)(ws + OFF_TOPI);
  int* perm = (int*)(ws + OFF_PERM);
  int* pos  = (int*)(ws + OFF_POS);
  unsigned short* xg  = (unsigned short*)(ws + OFF_XG);
  unsigned short* h   = (unsigned short*)(ws + OFF_H);
  unsigned short* w1t = (unsigned short*)(ws + OFF_W1T);
  unsigned short* w2t = (unsigned short*)(ws + OFF_W2T);

  hipLaunchKernelGGL(gate_kernel, dim3(NTOK / 4), dim3(256), 0, stream, x, gw, gb, eb, topi);
  hipLaunchKernelGGL(rank_kernel, dim3(1), dim3(1024), 0, stream, topi, meta, pos, perm);
  hipLaunchKernelGGL(scatter_kernel, dim3(NTOK), dim3(256), 0, stream, x, pos, xg);
  hipLaunchKernelGGL(transconv2, dim3(D_FF / 64, D_MODEL / 64, NEXP), dim3(256), 0, stream,
                     w1, w1t, D_MODEL, D_FF);
  hipLaunchKernelGGL(transconv2, dim3(D_MODEL / 64, D_FF / 64, NEXP), dim3(256), 0, stream,
                     w2, w2t, D_FF, D_MODEL);
  hipLaunchKernelGGL((gemm4<D_MODEL, D_FF, true>), dim3(MAXT128 * (D_FF / 128)), dim3(256), 0, stream,
                     xg, w1t, b1, meta, perm, h, nullptr);
  hipLaunchKernelGGL((gemm4<D_FF, D_MODEL, false>), dim3(MAXT128 * (D_MODEL / 128)), dim3(256), 0, stream,
                     h, w2t, b2, meta, perm, nullptr, out);
}